// Round 6
// baseline (832.872 us; speedup 1.0000x reference)
//
#include <hip/hip_runtime.h>
#include <math.h>

typedef __attribute__((ext_vector_type(8))) short bf16x8;
typedef __attribute__((ext_vector_type(4))) float f32x4;

#define GAT_ALPHA 0.2f

static __device__ __forceinline__ unsigned short f2bf(float x) {
    unsigned u = __float_as_uint(x);
    u += 0x7fffu + ((u >> 16) & 1u);   // RNE; inputs are finite & non-NaN
    return (unsigned short)(u >> 16);
}
static __device__ __forceinline__ float bf2f(unsigned short b) {
    return __uint_as_float(((unsigned)b) << 16);
}

// ---------------- k_prep: h = input @ W (f32), per-row {rowsum, ss=h.c2, sd=h.c1}
__global__ __launch_bounds__(512)
void k_prep(const float* __restrict__ input, const float* __restrict__ W,
            const float* __restrict__ c1, const float* __restrict__ c2,
            unsigned short* __restrict__ hb, float* __restrict__ ssx,
            float* __restrict__ sd, int N, int Fin, int Fout)
{
    __shared__ float in_lds[4][256];
    __shared__ float red[4][3];
    const int tid = threadIdx.x;
    const int r0 = blockIdx.x * 4;
    for (int idx = tid; idx < 4 * Fin; idx += 512) {
        int r = idx / Fin, c = idx - r * Fin;
        in_lds[r][c] = input[(size_t)(r0 + r) * Fin + c];
    }
    if (tid < 12) ((float*)red)[tid] = 0.f;
    __syncthreads();
    const int y = tid >> 7, f = tid & 127;
    float acc = 0.f;
    for (int k = 0; k < Fin; ++k)
        acc = fmaf(in_lds[y][k], W[(size_t)k * Fout + f], acc);
    const int row = r0 + y;
    hb[(size_t)row * Fout + f] = f2bf(acc);
    float rs = acc, sv = acc * c2[f], dv = acc * c1[f];
    for (int off = 32; off > 0; off >>= 1) {
        rs += __shfl_xor(rs, off);
        sv += __shfl_xor(sv, off);
        dv += __shfl_xor(dv, off);
    }
    if ((tid & 63) == 0) {
        atomicAdd(&red[y][0], rs);
        atomicAdd(&red[y][1], sv);
        atomicAdd(&red[y][2], dv);
    }
    __syncthreads();
    if (f == 0) {
        float rsum = red[y][0];
        ssx[row] = (rsum != 0.f) ? red[y][1] : -1e30f;  // fold j-mask into score
        sd[row]  = red[y][2];
    }
}

// ---------------- k_smax: global masked max of ssx
__global__ __launch_bounds__(1024)
void k_smax(const float* __restrict__ ssx, float* __restrict__ smax, int N)
{
    __shared__ float red[16];
    const int tid = threadIdx.x;
    float m = -3e38f;
    for (int i = tid; i < N; i += 1024) m = fmaxf(m, ssx[i]);
    for (int off = 32; off > 0; off >>= 1) m = fmaxf(m, __shfl_xor(m, off));
    if ((tid & 63) == 0) red[tid >> 6] = m;
    __syncthreads();
    if (tid == 0) {
        float mm = red[0];
        for (int i = 1; i < 16; ++i) mm = fmaxf(mm, red[i]);
        smax[0] = mm;
    }
}

// ---------------- k_transpose: hb [N][Fout] -> ht [Fout][N]
__global__ __launch_bounds__(256)
void k_transpose(const unsigned short* __restrict__ hb, unsigned short* __restrict__ ht,
                 int N, int Fout)
{
    __shared__ unsigned short t[64][65];
    const int bx = blockIdx.x;   // N/64
    const int by = blockIdx.y;   // Fout/64
    const int tid = threadIdx.x;
    for (int i = 0; i < 16; ++i) {
        int idx = i * 256 + tid; int r = idx >> 6, c = idx & 63;
        t[r][c] = hb[(size_t)(bx * 64 + r) * Fout + by * 64 + c];
    }
    __syncthreads();
    for (int i = 0; i < 16; ++i) {
        int idx = i * 256 + tid; int r = idx >> 6, c = idx & 63;
        ht[(size_t)(by * 64 + r) * N + bx * 64 + c] = t[c][r];
    }
}

// ---------------- k_attn: BM=256 rows/block, grid (M/256, NSPLIT).
// Phase 1: bitpack 256 x chunk adj slice into LDS (each adj elem read once
// device-wide, coalesced). Phase 2: per 32-j step, cooperatively stage the
// SHARED B-tile (128x32 bf16 = 8KB) into double-buffered swizzled LDS; 8
// row-split waves (32 rows each) consume it. One barrier/step. Epilogue:
// fragment-major bf16 numerator partials (coalesced), f32 denom partials.
__global__ __launch_bounds__(512, 8)
void k_attn(const int* __restrict__ adj, const unsigned short* __restrict__ ht,
            const float* __restrict__ ssx, const float* __restrict__ sd,
            const float* __restrict__ smaxp, unsigned short* __restrict__ part,
            float* __restrict__ dpart, int N, int M, int chunk)
{
    extern __shared__ char smem[];
    unsigned* bits = (unsigned*)smem;                  // 256 * chunk/32 words
    char* btile = smem + 256 * (chunk >> 3);           // 2 x 8192 B

    const int tid = threadIdx.x;
    const int rb  = blockIdx.x * 256;
    const int j0  = blockIdx.y * chunk;
    const int wpr = chunk >> 5;                        // bitmask words per row
    const int NT  = wpr;                               // 32-j steps

    // ---- phase 1: bitpack adj[rb..rb+256)[j0..j0+chunk) into LDS
    {
        const int gpr = chunk >> 3;                    // 8-int groups per row
        const int groups = 256 * gpr;
        for (int g = tid; g < groups; g += 512) {
            int rl = g / gpr;
            int jg = g - rl * gpr;
            const int* ap = adj + (size_t)(rb + rl) * N + j0 + jg * 8;
            int4 v0 = *(const int4*)ap;
            int4 v1 = *(const int4*)(ap + 4);
            unsigned b = (unsigned)(v0.x > 0)        | ((unsigned)(v0.y > 0) << 1)
                       | ((unsigned)(v0.z > 0) << 2) | ((unsigned)(v0.w > 0) << 3)
                       | ((unsigned)(v1.x > 0) << 4) | ((unsigned)(v1.y > 0) << 5)
                       | ((unsigned)(v1.z > 0) << 6) | ((unsigned)(v1.w > 0) << 7);
            int wj = jg >> 2;                           // word index in row
            ((unsigned char*)smem)[rl * gpr + ((wj ^ (rl & 7)) << 2) + (jg & 3)] =
                (unsigned char)b;
        }
    }

    // ---- phase 2 setup
    const int w  = tid >> 6;           // wave 0..7 -> rows [w*32, w*32+32)
    const int l  = tid & 63;
    const int am = l & 15;
    const int kg = l >> 4;
    const int ams = am & 7;

    const int rl0 = w * 32 + am, rl1 = rl0 + 16;
    const int r0 = rb + rl0, r1 = rb + rl1;
    const float s0 = sd[r0], s1 = sd[r1];
    const float sm = smaxp[0];
    const float vb0 = s0 + sm, vb1 = s1 + sm;
    const float m0 = fmaxf(vb0, GAT_ALPHA * vb0);
    const float m1 = fmaxf(vb1, GAT_ALPHA * vb1);

    const int bw0 = rl0 * wpr, bw1 = rl1 * wpr;
    const float* __restrict__ sbase = ssx + j0 + 8 * kg;

    // staging role: thread -> (f = tid>>2, jp = tid&3), 16B of ht per step
    const int fw = tid >> 2, jp = tid & 3;
    const unsigned short* __restrict__ gstage = ht + (size_t)fw * N + j0 + jp * 8;
    const int cw = fw >> 4, amw = fw & 15;
    const int wslot = (((cw & 1) << 2) | jp) ^ (amw & 7);
    const int waddr = (fw >> 5) * 2048 + amw * 128 + wslot * 16;

    // B-frag read byte offsets (8KB buffer local)
    int raddr[8];
    #pragma unroll
    for (int c = 0; c < 8; ++c)
        raddr[c] = (c >> 1) * 2048 + am * 128 + (((((c & 1) << 2)) | kg) ^ ams) * 16;

    f32x4 acc0[8], acc1[8];
    #pragma unroll
    for (int c = 0; c < 8; ++c) {
        acc0[c] = (f32x4){0.f, 0.f, 0.f, 0.f};
        acc1[c] = (f32x4){0.f, 0.f, 0.f, 0.f};
    }
    float d0 = 0.f, d1 = 0.f;

    __syncthreads();   // bits ready; also before first btile write

    // prologue: REG = B-tile 0 slice; ssx step 0
    bf16x8 REG = *(const bf16x8*)gstage;
    float4 sC0 = *(const float4*)(sbase);
    float4 sC1 = *(const float4*)(sbase + 4);
    float4 sN0, sN1;

    auto PBUILD = [&](unsigned bw, float ss, float mm,
                      const float4& u0, const float4& u1, float& dacc) -> bf16x8 {
        bf16x8 af;
        unsigned short* pu = (unsigned short*)&af;
        const float* f0 = (const float*)&u0;
        const float* f1 = (const float*)&u1;
        float d = 0.f;
        #pragma unroll
        for (int i = 0; i < 4; ++i) {
            float v = ss + f0[i];
            float e = fminf(fmaxf(v, GAT_ALPHA * v) - mm, 0.f);
            float p = (bw & (1u << i)) ? __expf(e) : 0.f;
            pu[i] = f2bf(p); d += p;
        }
        #pragma unroll
        for (int i = 0; i < 4; ++i) {
            float v = ss + f1[i];
            float e = fminf(fmaxf(v, GAT_ALPHA * v) - mm, 0.f);
            float p = (bw & (16u << i)) ? __expf(e) : 0.f;
            pu[4 + i] = f2bf(p); d += p;
        }
        dacc += d;
        return af;
    };

    auto STEP = [&](int jt, int par, float4& p0, float4& p1, float4& q0, float4& q1) {
        // stage this step's B-tile slice (REG loaded last step)
        *(bf16x8*)(btile + par * 8192 + waddr) = REG;
        // issue next step's loads
        const int nj = ((jt + 1 < NT) ? jt + 1 : 0) * 32;
        REG = *(const bf16x8*)(gstage + nj);
        q0 = *(const float4*)(sbase + nj);
        q1 = *(const float4*)(sbase + nj + 4);
        __syncthreads();
        // bitmask words (broadcast across kg quad)
        const unsigned bb0 = bits[bw0 + (jt ^ ams)] >> (8 * kg);
        const unsigned bb1 = bits[bw1 + (jt ^ ams)] >> (8 * kg);
        // B fragments from LDS (2-way max conflict)
        const char* bt = btile + par * 8192;
        bf16x8 b0 = *(const bf16x8*)(bt + raddr[0]);
        bf16x8 b1 = *(const bf16x8*)(bt + raddr[1]);
        bf16x8 b2 = *(const bf16x8*)(bt + raddr[2]);
        bf16x8 b3 = *(const bf16x8*)(bt + raddr[3]);
        bf16x8 b4 = *(const bf16x8*)(bt + raddr[4]);
        bf16x8 b5 = *(const bf16x8*)(bt + raddr[5]);
        bf16x8 b6 = *(const bf16x8*)(bt + raddr[6]);
        bf16x8 b7 = *(const bf16x8*)(bt + raddr[7]);
        // P fragments (exp chains)
        bf16x8 af0 = PBUILD(bb0, s0, m0, p0, p1, d0);
        bf16x8 af1 = PBUILD(bb1, s1, m1, p0, p1, d1);
        // 16 MFMAs
        acc0[0] = __builtin_amdgcn_mfma_f32_16x16x32_bf16(af0, b0, acc0[0], 0, 0, 0);
        acc0[1] = __builtin_amdgcn_mfma_f32_16x16x32_bf16(af0, b1, acc0[1], 0, 0, 0);
        acc0[2] = __builtin_amdgcn_mfma_f32_16x16x32_bf16(af0, b2, acc0[2], 0, 0, 0);
        acc0[3] = __builtin_amdgcn_mfma_f32_16x16x32_bf16(af0, b3, acc0[3], 0, 0, 0);
        acc0[4] = __builtin_amdgcn_mfma_f32_16x16x32_bf16(af0, b4, acc0[4], 0, 0, 0);
        acc0[5] = __builtin_amdgcn_mfma_f32_16x16x32_bf16(af0, b5, acc0[5], 0, 0, 0);
        acc0[6] = __builtin_amdgcn_mfma_f32_16x16x32_bf16(af0, b6, acc0[6], 0, 0, 0);
        acc0[7] = __builtin_amdgcn_mfma_f32_16x16x32_bf16(af0, b7, acc0[7], 0, 0, 0);
        acc1[0] = __builtin_amdgcn_mfma_f32_16x16x32_bf16(af1, b0, acc1[0], 0, 0, 0);
        acc1[1] = __builtin_amdgcn_mfma_f32_16x16x32_bf16(af1, b1, acc1[1], 0, 0, 0);
        acc1[2] = __builtin_amdgcn_mfma_f32_16x16x32_bf16(af1, b2, acc1[2], 0, 0, 0);
        acc1[3] = __builtin_amdgcn_mfma_f32_16x16x32_bf16(af1, b3, acc1[3], 0, 0, 0);
        acc1[4] = __builtin_amdgcn_mfma_f32_16x16x32_bf16(af1, b4, acc1[4], 0, 0, 0);
        acc1[5] = __builtin_amdgcn_mfma_f32_16x16x32_bf16(af1, b5, acc1[5], 0, 0, 0);
        acc1[6] = __builtin_amdgcn_mfma_f32_16x16x32_bf16(af1, b6, acc1[6], 0, 0, 0);
        acc1[7] = __builtin_amdgcn_mfma_f32_16x16x32_bf16(af1, b7, acc1[7], 0, 0, 0);
    };

    for (int jt = 0; jt + 1 < NT; jt += 2) {
        STEP(jt,     0, sC0, sC1, sN0, sN1);
        STEP(jt + 1, 1, sN0, sN1, sC0, sC1);
    }
    if (NT & 1) STEP(NT - 1, 0, sC0, sC1, sN0, sN1);

    // ---- epilogue: denom partials (f32) + fragment-major numerator partials (bf16)
    d0 += __shfl_xor(d0, 16); d0 += __shfl_xor(d0, 32);
    d1 += __shfl_xor(d1, 16); d1 += __shfl_xor(d1, 32);
    if (kg == 0) {
        dpart[(size_t)blockIdx.y * M + r0] = d0;
        dpart[(size_t)blockIdx.y * M + r1] = d1;
    }

    unsigned short* pb = part + (size_t)blockIdx.y * M * 128
                       + ((((size_t)blockIdx.x * 8 + w) * 64 + l) * 64);
    #pragma unroll
    for (int ec = 0; ec < 8; ++ec) {
        const int strip = ec >> 2, c0 = (ec & 3) * 2;
        const f32x4 x = strip ? acc1[c0]     : acc0[c0];
        const f32x4 y = strip ? acc1[c0 + 1] : acc0[c0 + 1];
        bf16x8 pv;
        unsigned short* pp = (unsigned short*)&pv;
        pp[0] = f2bf(x[0]); pp[1] = f2bf(x[1]); pp[2] = f2bf(x[2]); pp[3] = f2bf(x[3]);
        pp[4] = f2bf(y[0]); pp[5] = f2bf(y[1]); pp[6] = f2bf(y[2]); pp[7] = f2bf(y[3]);
        *(bf16x8*)(pb + ec * 8) = pv;
    }
}

// ---------------- k_dsum: denom[r] = sum_s dpart[s][r]
__global__ __launch_bounds__(256)
void k_dsum(const float* __restrict__ dpart, float* __restrict__ denom, int M, int NS)
{
    const int r = blockIdx.x * 256 + threadIdx.x;
    if (r < M) {
        float d = 0.f;
        for (int s = 0; s < NS; ++s) d += dpart[(size_t)s * M + r];
        denom[r] = d;
    }
}

// ---------------- k_combine: out = elu( (sum_s part[s]) / denom[row] )
__global__ __launch_bounds__(256)
void k_combine(const unsigned short* __restrict__ part, const float* __restrict__ denom,
               float* __restrict__ out, int M, int NS)
{
    const int idx = blockIdx.x * 256 + threadIdx.x;       // 0 .. M*128/8
    const int rbk = idx >> 12, w = (idx >> 9) & 7, l = (idx >> 3) & 63, ec = idx & 7;
    const int am = l & 15, kg = l >> 4, strip = ec >> 2, c0 = (ec & 3) * 2;

    float sums[8] = {0.f, 0.f, 0.f, 0.f, 0.f, 0.f, 0.f, 0.f};
    const unsigned short* p = part + (size_t)idx * 8;
    for (int s = 0; s < NS; ++s) {
        bf16x8 v = *(const bf16x8*)(p + (size_t)s * M * 128);
        const unsigned short* vp = (const unsigned short*)&v;
        #pragma unroll
        for (int i = 0; i < 8; ++i) sums[i] += bf2f(vp[i]);
    }
    const int rbase = rbk * 256 + w * 32 + strip * 16 + kg * 4;
    #pragma unroll
    for (int reg = 0; reg < 4; ++reg) {
        const float dd = denom[rbase + reg];
        const float inv = (dd > 0.f) ? 1.f / dd : 0.f;
        #pragma unroll
        for (int half = 0; half < 2; ++half) {
            float x = sums[half * 4 + reg] * inv;
            x = (x > 0.f) ? x : expm1f(x);
            out[(size_t)(rbase + reg) * 128 + (c0 + half) * 16 + am] = x;
        }
    }
}

extern "C" void kernel_launch(void* const* d_in, const int* in_sizes, int n_in,
                              void* d_out, int out_size, void* d_ws, size_t ws_size,
                              hipStream_t stream)
{
    const float* input = (const float*)d_in[0];
    const float* W     = (const float*)d_in[1];
    const float* c1    = (const float*)d_in[2];
    const float* c2    = (const float*)d_in[3];
    const int*   adj   = (const int*)d_in[4];

    const int Fout = in_sizes[2];          // c1: [Fout,1]
    const int Fin  = in_sizes[1] / Fout;   // W: [Fin,Fout]
    const int N    = in_sizes[0] / Fin;    // input: [N,Fin]
    const int M    = out_size / Fout;
    float* out = (float*)d_out;

    char* ws = (char*)d_ws;
    const size_t o_hb   = 0;
    const size_t o_ht   = o_hb + (size_t)N * Fout * 2;
    const size_t o_ssx  = o_ht + (size_t)N * Fout * 2;
    const size_t o_sd   = o_ssx + (size_t)N * 4;
    const size_t o_smax = o_sd + (size_t)N * 4;
    const size_t o_den  = o_smax + 64;
    const size_t o_dpart = o_den + ((size_t)M * 4 + 63 & ~63ULL);

    int NS = 16;
    size_t o_part = 0;
    while (NS >= 1) {
        size_t op = (o_dpart + (size_t)NS * M * 4 + 15) & ~15ULL;
        if (op + (size_t)NS * M * Fout * 2 <= ws_size) { o_part = op; break; }
        NS >>= 1;
    }
    const int chunk = N / NS;

    unsigned short* hb = (unsigned short*)(ws + o_hb);
    unsigned short* ht = (unsigned short*)(ws + o_ht);
    float* ssx   = (float*)(ws + o_ssx);
    float* sd    = (float*)(ws + o_sd);
    float* smax  = (float*)(ws + o_smax);
    float* denom = (float*)(ws + o_den);
    float* dpart = (float*)(ws + o_dpart);
    unsigned short* part = (unsigned short*)(ws + o_part);

    k_prep<<<N / 4, 512, 0, stream>>>(input, W, c1, c2, hb, ssx, sd, N, Fin, Fout);
    k_smax<<<1, 1024, 0, stream>>>(ssx, smax, N);
    k_transpose<<<dim3(N / 64, Fout / 64), 256, 0, stream>>>(hb, ht, N, Fout);

    const size_t smem_bytes = 256 * (size_t)(chunk >> 3) + 2 * 8192;
    k_attn<<<dim3(M / 256, NS), 512, smem_bytes, stream>>>(
        adj, ht, ssx, sd, smax, part, dpart, N, M, chunk);

    k_dsum<<<(M + 255) / 256, 256, 0, stream>>>(dpart, denom, M, NS);
    k_combine<<<M * Fout / 8 / 256, 256, 0, stream>>>(part, denom, out, M, NS);
}

// Round 7
// 165.386 us; speedup vs baseline: 5.0359x; 5.0359x over previous
//
#include <hip/hip_runtime.h>
#include <math.h>

typedef __attribute__((ext_vector_type(8))) short bf16x8;
typedef __attribute__((ext_vector_type(4))) float f32x4;

#define GAT_ALPHA 0.2f

static __device__ __forceinline__ unsigned short f2bf(float x) {
    unsigned u = __float_as_uint(x);
    u += 0x7fffu + ((u >> 16) & 1u);   // RNE; inputs are finite & non-NaN
    return (unsigned short)(u >> 16);
}
static __device__ __forceinline__ float bf2f(unsigned short b) {
    return __uint_as_float(((unsigned)b) << 16);
}

// ---------------- k_prep: h = input @ W (f32), per-row {rowsum, ss=h.c2, sd=h.c1}
__global__ __launch_bounds__(512)
void k_prep(const float* __restrict__ input, const float* __restrict__ W,
            const float* __restrict__ c1, const float* __restrict__ c2,
            unsigned short* __restrict__ hb, float* __restrict__ ssx,
            float* __restrict__ sd, int N, int Fin, int Fout)
{
    __shared__ float in_lds[4][256];
    __shared__ float red[4][3];
    const int tid = threadIdx.x;
    const int r0 = blockIdx.x * 4;
    for (int idx = tid; idx < 4 * Fin; idx += 512) {
        int r = idx / Fin, c = idx - r * Fin;
        in_lds[r][c] = input[(size_t)(r0 + r) * Fin + c];
    }
    if (tid < 12) ((float*)red)[tid] = 0.f;
    __syncthreads();
    const int y = tid >> 7, f = tid & 127;
    float acc = 0.f;
    for (int k = 0; k < Fin; ++k)
        acc = fmaf(in_lds[y][k], W[(size_t)k * Fout + f], acc);
    const int row = r0 + y;
    hb[(size_t)row * Fout + f] = f2bf(acc);
    float rs = acc, sv = acc * c2[f], dv = acc * c1[f];
    for (int off = 32; off > 0; off >>= 1) {
        rs += __shfl_xor(rs, off);
        sv += __shfl_xor(sv, off);
        dv += __shfl_xor(dv, off);
    }
    if ((tid & 63) == 0) {
        atomicAdd(&red[y][0], rs);
        atomicAdd(&red[y][1], sv);
        atomicAdd(&red[y][2], dv);
    }
    __syncthreads();
    if (f == 0) {
        float rsum = red[y][0];
        ssx[row] = (rsum != 0.f) ? red[y][1] : -1e30f;  // fold j-mask into score
        sd[row]  = red[y][2];
    }
}

// ---------------- k_smax: global masked max of ssx
__global__ __launch_bounds__(1024)
void k_smax(const float* __restrict__ ssx, float* __restrict__ smax, int N)
{
    __shared__ float red[16];
    const int tid = threadIdx.x;
    float m = -3e38f;
    for (int i = tid; i < N; i += 1024) m = fmaxf(m, ssx[i]);
    for (int off = 32; off > 0; off >>= 1) m = fmaxf(m, __shfl_xor(m, off));
    if ((tid & 63) == 0) red[tid >> 6] = m;
    __syncthreads();
    if (tid == 0) {
        float mm = red[0];
        for (int i = 1; i < 16; ++i) mm = fmaxf(mm, red[i]);
        smax[0] = mm;
    }
}

// ---------------- k_transpose: hb [N][Fout] -> ht [Fout][N]
__global__ __launch_bounds__(256)
void k_transpose(const unsigned short* __restrict__ hb, unsigned short* __restrict__ ht,
                 int N, int Fout)
{
    __shared__ unsigned short t[64][65];
    const int bx = blockIdx.x;   // N/64
    const int by = blockIdx.y;   // Fout/64
    const int tid = threadIdx.x;
    for (int i = 0; i < 16; ++i) {
        int idx = i * 256 + tid; int r = idx >> 6, c = idx & 63;
        t[r][c] = hb[(size_t)(bx * 64 + r) * Fout + by * 64 + c];
    }
    __syncthreads();
    for (int i = 0; i < 16; ++i) {
        int idx = i * 256 + tid; int r = idx >> 6, c = idx & 63;
        ht[(size_t)(by * 64 + r) * N + bx * 64 + c] = t[c][r];
    }
}

// ---------------- k_attn: BM=256 rows/block, grid (M/256, NSPLIT).
// Phase 1: bitpack 256 x chunk adj slice into LDS (each adj elem read once
// device-wide, coalesced). Phase 2: per 32-j step, cooperatively stage the
// SHARED B-tile (128x32 bf16 = 8KB) into double-buffered swizzled LDS; 8
// row-split waves (32 rows each) consume it. One barrier/step. Epilogue:
// fragment-major bf16 numerator partials (coalesced), f32 denom partials.
// launch_bounds(512,2): VGPR cap 256 -- acc needs 64+; (512,8) caused total
// spill to scratch in R6 (VGPR=32, 2.4GB spill traffic).
__global__ __launch_bounds__(512, 2)
void k_attn(const int* __restrict__ adj, const unsigned short* __restrict__ ht,
            const float* __restrict__ ssx, const float* __restrict__ sd,
            const float* __restrict__ smaxp, unsigned short* __restrict__ part,
            float* __restrict__ dpart, int N, int M, int chunk)
{
    extern __shared__ char smem[];
    unsigned* bits = (unsigned*)smem;                  // 256 * chunk/32 words
    char* btile = smem + 256 * (chunk >> 3);           // 2 x 8192 B

    const int tid = threadIdx.x;
    const int rb  = blockIdx.x * 256;
    const int j0  = blockIdx.y * chunk;
    const int wpr = chunk >> 5;                        // bitmask words per row
    const int NT  = wpr;                               // 32-j steps

    // ---- phase 1: bitpack adj[rb..rb+256)[j0..j0+chunk) into LDS
    {
        const int gpr = chunk >> 3;                    // 8-int groups per row
        const int groups = 256 * gpr;
        for (int g = tid; g < groups; g += 512) {
            int rl = g / gpr;
            int jg = g - rl * gpr;
            const int* ap = adj + (size_t)(rb + rl) * N + j0 + jg * 8;
            int4 v0 = *(const int4*)ap;
            int4 v1 = *(const int4*)(ap + 4);
            unsigned b = (unsigned)(v0.x > 0)        | ((unsigned)(v0.y > 0) << 1)
                       | ((unsigned)(v0.z > 0) << 2) | ((unsigned)(v0.w > 0) << 3)
                       | ((unsigned)(v1.x > 0) << 4) | ((unsigned)(v1.y > 0) << 5)
                       | ((unsigned)(v1.z > 0) << 6) | ((unsigned)(v1.w > 0) << 7);
            int wj = jg >> 2;                           // word index in row
            ((unsigned char*)smem)[rl * gpr + ((wj ^ (rl & 7)) << 2) + (jg & 3)] =
                (unsigned char)b;
        }
    }

    // ---- phase 2 setup
    const int w  = tid >> 6;           // wave 0..7 -> rows [w*32, w*32+32)
    const int l  = tid & 63;
    const int am = l & 15;
    const int kg = l >> 4;
    const int ams = am & 7;

    const int rl0 = w * 32 + am, rl1 = rl0 + 16;
    const int r0 = rb + rl0, r1 = rb + rl1;
    const float s0 = sd[r0], s1 = sd[r1];
    const float sm = smaxp[0];
    const float vb0 = s0 + sm, vb1 = s1 + sm;
    const float m0 = fmaxf(vb0, GAT_ALPHA * vb0);
    const float m1 = fmaxf(vb1, GAT_ALPHA * vb1);

    const int bw0 = rl0 * wpr, bw1 = rl1 * wpr;
    const float* __restrict__ sbase = ssx + j0 + 8 * kg;

    // staging role: thread -> (f = tid>>2, jp = tid&3), 16B of ht per step
    const int fw = tid >> 2, jp = tid & 3;
    const unsigned short* __restrict__ gstage = ht + (size_t)fw * N + j0 + jp * 8;
    const int cw = fw >> 4, amw = fw & 15;
    const int wslot = (((cw & 1) << 2) | jp) ^ (amw & 7);
    const int waddr = (fw >> 5) * 2048 + amw * 128 + wslot * 16;

    // B-frag read byte offsets (8KB buffer local)
    int raddr[8];
    #pragma unroll
    for (int c = 0; c < 8; ++c)
        raddr[c] = (c >> 1) * 2048 + am * 128 + (((((c & 1) << 2)) | kg) ^ ams) * 16;

    f32x4 acc0[8], acc1[8];
    #pragma unroll
    for (int c = 0; c < 8; ++c) {
        acc0[c] = (f32x4){0.f, 0.f, 0.f, 0.f};
        acc1[c] = (f32x4){0.f, 0.f, 0.f, 0.f};
    }
    float d0 = 0.f, d1 = 0.f;

    __syncthreads();   // bits ready; also before first btile write

    // prologue: REG = B-tile 0 slice; ssx step 0
    bf16x8 REG = *(const bf16x8*)gstage;
    float4 sC0 = *(const float4*)(sbase);
    float4 sC1 = *(const float4*)(sbase + 4);
    float4 sN0, sN1;

    auto PBUILD = [&](unsigned bw, float ss, float mm,
                      const float4& u0, const float4& u1, float& dacc) -> bf16x8 {
        bf16x8 af;
        unsigned short* pu = (unsigned short*)&af;
        const float* f0 = (const float*)&u0;
        const float* f1 = (const float*)&u1;
        float d = 0.f;
        #pragma unroll
        for (int i = 0; i < 4; ++i) {
            float v = ss + f0[i];
            float e = fminf(fmaxf(v, GAT_ALPHA * v) - mm, 0.f);
            float p = (bw & (1u << i)) ? __expf(e) : 0.f;
            pu[i] = f2bf(p); d += p;
        }
        #pragma unroll
        for (int i = 0; i < 4; ++i) {
            float v = ss + f1[i];
            float e = fminf(fmaxf(v, GAT_ALPHA * v) - mm, 0.f);
            float p = (bw & (16u << i)) ? __expf(e) : 0.f;
            pu[4 + i] = f2bf(p); d += p;
        }
        dacc += d;
        return af;
    };

    auto STEP = [&](int jt, int par, float4& p0, float4& p1, float4& q0, float4& q1) {
        // stage this step's B-tile slice (REG loaded last step)
        *(bf16x8*)(btile + par * 8192 + waddr) = REG;
        // issue next step's loads
        const int nj = ((jt + 1 < NT) ? jt + 1 : 0) * 32;
        REG = *(const bf16x8*)(gstage + nj);
        q0 = *(const float4*)(sbase + nj);
        q1 = *(const float4*)(sbase + nj + 4);
        __syncthreads();
        // bitmask words (broadcast across kg quad)
        const unsigned bb0 = bits[bw0 + (jt ^ ams)] >> (8 * kg);
        const unsigned bb1 = bits[bw1 + (jt ^ ams)] >> (8 * kg);
        // B fragments from LDS (2-way max conflict)
        const char* bt = btile + par * 8192;
        bf16x8 b0 = *(const bf16x8*)(bt + raddr[0]);
        bf16x8 b1 = *(const bf16x8*)(bt + raddr[1]);
        bf16x8 b2 = *(const bf16x8*)(bt + raddr[2]);
        bf16x8 b3 = *(const bf16x8*)(bt + raddr[3]);
        bf16x8 b4 = *(const bf16x8*)(bt + raddr[4]);
        bf16x8 b5 = *(const bf16x8*)(bt + raddr[5]);
        bf16x8 b6 = *(const bf16x8*)(bt + raddr[6]);
        bf16x8 b7 = *(const bf16x8*)(bt + raddr[7]);
        // P fragments (exp chains)
        bf16x8 af0 = PBUILD(bb0, s0, m0, p0, p1, d0);
        bf16x8 af1 = PBUILD(bb1, s1, m1, p0, p1, d1);
        // 16 MFMAs
        acc0[0] = __builtin_amdgcn_mfma_f32_16x16x32_bf16(af0, b0, acc0[0], 0, 0, 0);
        acc0[1] = __builtin_amdgcn_mfma_f32_16x16x32_bf16(af0, b1, acc0[1], 0, 0, 0);
        acc0[2] = __builtin_amdgcn_mfma_f32_16x16x32_bf16(af0, b2, acc0[2], 0, 0, 0);
        acc0[3] = __builtin_amdgcn_mfma_f32_16x16x32_bf16(af0, b3, acc0[3], 0, 0, 0);
        acc0[4] = __builtin_amdgcn_mfma_f32_16x16x32_bf16(af0, b4, acc0[4], 0, 0, 0);
        acc0[5] = __builtin_amdgcn_mfma_f32_16x16x32_bf16(af0, b5, acc0[5], 0, 0, 0);
        acc0[6] = __builtin_amdgcn_mfma_f32_16x16x32_bf16(af0, b6, acc0[6], 0, 0, 0);
        acc0[7] = __builtin_amdgcn_mfma_f32_16x16x32_bf16(af0, b7, acc0[7], 0, 0, 0);
        acc1[0] = __builtin_amdgcn_mfma_f32_16x16x32_bf16(af1, b0, acc1[0], 0, 0, 0);
        acc1[1] = __builtin_amdgcn_mfma_f32_16x16x32_bf16(af1, b1, acc1[1], 0, 0, 0);
        acc1[2] = __builtin_amdgcn_mfma_f32_16x16x32_bf16(af1, b2, acc1[2], 0, 0, 0);
        acc1[3] = __builtin_amdgcn_mfma_f32_16x16x32_bf16(af1, b3, acc1[3], 0, 0, 0);
        acc1[4] = __builtin_amdgcn_mfma_f32_16x16x32_bf16(af1, b4, acc1[4], 0, 0, 0);
        acc1[5] = __builtin_amdgcn_mfma_f32_16x16x32_bf16(af1, b5, acc1[5], 0, 0, 0);
        acc1[6] = __builtin_amdgcn_mfma_f32_16x16x32_bf16(af1, b6, acc1[6], 0, 0, 0);
        acc1[7] = __builtin_amdgcn_mfma_f32_16x16x32_bf16(af1, b7, acc1[7], 0, 0, 0);
    };

    for (int jt = 0; jt + 1 < NT; jt += 2) {
        STEP(jt,     0, sC0, sC1, sN0, sN1);
        STEP(jt + 1, 1, sN0, sN1, sC0, sC1);
    }
    if (NT & 1) STEP(NT - 1, 0, sC0, sC1, sN0, sN1);

    // ---- epilogue: denom partials (f32) + fragment-major numerator partials (bf16)
    d0 += __shfl_xor(d0, 16); d0 += __shfl_xor(d0, 32);
    d1 += __shfl_xor(d1, 16); d1 += __shfl_xor(d1, 32);
    if (kg == 0) {
        dpart[(size_t)blockIdx.y * M + r0] = d0;
        dpart[(size_t)blockIdx.y * M + r1] = d1;
    }

    unsigned short* pb = part + (size_t)blockIdx.y * M * 128
                       + ((((size_t)blockIdx.x * 8 + w) * 64 + l) * 64);
    #pragma unroll
    for (int ec = 0; ec < 8; ++ec) {
        const int strip = ec >> 2, c0 = (ec & 3) * 2;
        const f32x4 x = strip ? acc1[c0]     : acc0[c0];
        const f32x4 y = strip ? acc1[c0 + 1] : acc0[c0 + 1];
        bf16x8 pv;
        unsigned short* pp = (unsigned short*)&pv;
        pp[0] = f2bf(x[0]); pp[1] = f2bf(x[1]); pp[2] = f2bf(x[2]); pp[3] = f2bf(x[3]);
        pp[4] = f2bf(y[0]); pp[5] = f2bf(y[1]); pp[6] = f2bf(y[2]); pp[7] = f2bf(y[3]);
        *(bf16x8*)(pb + ec * 8) = pv;
    }
}

// ---------------- k_dsum: denom[r] = sum_s dpart[s][r]
__global__ __launch_bounds__(256)
void k_dsum(const float* __restrict__ dpart, float* __restrict__ denom, int M, int NS)
{
    const int r = blockIdx.x * 256 + threadIdx.x;
    if (r < M) {
        float d = 0.f;
        for (int s = 0; s < NS; ++s) d += dpart[(size_t)s * M + r];
        denom[r] = d;
    }
}

// ---------------- k_combine: out = elu( (sum_s part[s]) / denom[row] )
__global__ __launch_bounds__(256)
void k_combine(const unsigned short* __restrict__ part, const float* __restrict__ denom,
               float* __restrict__ out, int M, int NS)
{
    const int idx = blockIdx.x * 256 + threadIdx.x;       // 0 .. M*128/8
    const int rbk = idx >> 12, w = (idx >> 9) & 7, l = (idx >> 3) & 63, ec = idx & 7;
    const int am = l & 15, kg = l >> 4, strip = ec >> 2, c0 = (ec & 3) * 2;

    float sums[8] = {0.f, 0.f, 0.f, 0.f, 0.f, 0.f, 0.f, 0.f};
    const unsigned short* p = part + (size_t)idx * 8;
    for (int s = 0; s < NS; ++s) {
        bf16x8 v = *(const bf16x8*)(p + (size_t)s * M * 128);
        const unsigned short* vp = (const unsigned short*)&v;
        #pragma unroll
        for (int i = 0; i < 8; ++i) sums[i] += bf2f(vp[i]);
    }
    const int rbase = rbk * 256 + w * 32 + strip * 16 + kg * 4;
    #pragma unroll
    for (int reg = 0; reg < 4; ++reg) {
        const float dd = denom[rbase + reg];
        const float inv = (dd > 0.f) ? 1.f / dd : 0.f;
        #pragma unroll
        for (int half = 0; half < 2; ++half) {
            float x = sums[half * 4 + reg] * inv;
            x = (x > 0.f) ? x : expm1f(x);
            out[(size_t)(rbase + reg) * 128 + (c0 + half) * 16 + am] = x;
        }
    }
}

extern "C" void kernel_launch(void* const* d_in, const int* in_sizes, int n_in,
                              void* d_out, int out_size, void* d_ws, size_t ws_size,
                              hipStream_t stream)
{
    const float* input = (const float*)d_in[0];
    const float* W     = (const float*)d_in[1];
    const float* c1    = (const float*)d_in[2];
    const float* c2    = (const float*)d_in[3];
    const int*   adj   = (const int*)d_in[4];

    const int Fout = in_sizes[2];          // c1: [Fout,1]
    const int Fin  = in_sizes[1] / Fout;   // W: [Fin,Fout]
    const int N    = in_sizes[0] / Fin;    // input: [N,Fin]
    const int M    = out_size / Fout;
    float* out = (float*)d_out;

    char* ws = (char*)d_ws;
    const size_t o_hb   = 0;
    const size_t o_ht   = o_hb + (size_t)N * Fout * 2;
    const size_t o_ssx  = o_ht + (size_t)N * Fout * 2;
    const size_t o_sd   = o_ssx + (size_t)N * 4;
    const size_t o_smax = o_sd + (size_t)N * 4;
    const size_t o_den  = o_smax + 64;
    const size_t o_dpart = o_den + ((size_t)M * 4 + 63 & ~63ULL);

    int NS = 16;
    size_t o_part = 0;
    while (NS >= 1) {
        size_t op = (o_dpart + (size_t)NS * M * 4 + 15) & ~15ULL;
        if (op + (size_t)NS * M * Fout * 2 <= ws_size) { o_part = op; break; }
        NS >>= 1;
    }
    const int chunk = N / NS;

    unsigned short* hb = (unsigned short*)(ws + o_hb);
    unsigned short* ht = (unsigned short*)(ws + o_ht);
    float* ssx   = (float*)(ws + o_ssx);
    float* sd    = (float*)(ws + o_sd);
    float* smax  = (float*)(ws + o_smax);
    float* denom = (float*)(ws + o_den);
    float* dpart = (float*)(ws + o_dpart);
    unsigned short* part = (unsigned short*)(ws + o_part);

    k_prep<<<N / 4, 512, 0, stream>>>(input, W, c1, c2, hb, ssx, sd, N, Fin, Fout);
    k_smax<<<1, 1024, 0, stream>>>(ssx, smax, N);
    k_transpose<<<dim3(N / 64, Fout / 64), 256, 0, stream>>>(hb, ht, N, Fout);

    const size_t smem_bytes = 256 * (size_t)(chunk >> 3) + 2 * 8192;
    k_attn<<<dim3(M / 256, NS), 512, smem_bytes, stream>>>(
        adj, ht, ssx, sd, smax, part, dpart, N, M, chunk);

    k_dsum<<<(M + 255) / 256, 256, 0, stream>>>(dpart, denom, M, NS);
    k_combine<<<M * Fout / 8 / 256, 256, 0, stream>>>(part, denom, out, M, NS);
}

// Round 8
// 159.971 us; speedup vs baseline: 5.2064x; 1.0339x over previous
//
#include <hip/hip_runtime.h>
#include <math.h>

typedef __attribute__((ext_vector_type(8))) short bf16x8;
typedef __attribute__((ext_vector_type(4))) float f32x4;

#define GAT_ALPHA 0.2f

static __device__ __forceinline__ unsigned short f2bf(float x) {
    unsigned u = __float_as_uint(x);
    u += 0x7fffu + ((u >> 16) & 1u);   // RNE; inputs are finite & non-NaN
    return (unsigned short)(u >> 16);
}
static __device__ __forceinline__ float bf2f(unsigned short b) {
    return __uint_as_float(((unsigned)b) << 16);
}

// ---------------- k_prep: h = input @ W (f32), per-row {rowsum, ss=h.c2, sd=h.c1}
__global__ __launch_bounds__(512)
void k_prep(const float* __restrict__ input, const float* __restrict__ W,
            const float* __restrict__ c1, const float* __restrict__ c2,
            unsigned short* __restrict__ hb, float* __restrict__ ssx,
            float* __restrict__ sd, int N, int Fin, int Fout)
{
    __shared__ float in_lds[4][256];
    __shared__ float red[4][3];
    const int tid = threadIdx.x;
    const int r0 = blockIdx.x * 4;
    for (int idx = tid; idx < 4 * Fin; idx += 512) {
        int r = idx / Fin, c = idx - r * Fin;
        in_lds[r][c] = input[(size_t)(r0 + r) * Fin + c];
    }
    if (tid < 12) ((float*)red)[tid] = 0.f;
    __syncthreads();
    const int y = tid >> 7, f = tid & 127;
    float acc = 0.f;
    for (int k = 0; k < Fin; ++k)
        acc = fmaf(in_lds[y][k], W[(size_t)k * Fout + f], acc);
    const int row = r0 + y;
    hb[(size_t)row * Fout + f] = f2bf(acc);
    float rs = acc, sv = acc * c2[f], dv = acc * c1[f];
    for (int off = 32; off > 0; off >>= 1) {
        rs += __shfl_xor(rs, off);
        sv += __shfl_xor(sv, off);
        dv += __shfl_xor(dv, off);
    }
    if ((tid & 63) == 0) {
        atomicAdd(&red[y][0], rs);
        atomicAdd(&red[y][1], sv);
        atomicAdd(&red[y][2], dv);
    }
    __syncthreads();
    if (f == 0) {
        float rsum = red[y][0];
        ssx[row] = (rsum != 0.f) ? red[y][1] : -1e30f;  // fold j-mask into score
        sd[row]  = red[y][2];
    }
}

// ---------------- k_smax: global masked max of ssx
__global__ __launch_bounds__(1024)
void k_smax(const float* __restrict__ ssx, float* __restrict__ smax, int N)
{
    __shared__ float red[16];
    const int tid = threadIdx.x;
    float m = -3e38f;
    for (int i = tid; i < N; i += 1024) m = fmaxf(m, ssx[i]);
    for (int off = 32; off > 0; off >>= 1) m = fmaxf(m, __shfl_xor(m, off));
    if ((tid & 63) == 0) red[tid >> 6] = m;
    __syncthreads();
    if (tid == 0) {
        float mm = red[0];
        for (int i = 1; i < 16; ++i) mm = fmaxf(mm, red[i]);
        smax[0] = mm;
    }
}

// ---------------- k_transpose: hb [N][Fout] -> ht [Fout][N]
__global__ __launch_bounds__(256)
void k_transpose(const unsigned short* __restrict__ hb, unsigned short* __restrict__ ht,
                 int N, int Fout)
{
    __shared__ unsigned short t[64][65];
    const int bx = blockIdx.x;   // N/64
    const int by = blockIdx.y;   // Fout/64
    const int tid = threadIdx.x;
    for (int i = 0; i < 16; ++i) {
        int idx = i * 256 + tid; int r = idx >> 6, c = idx & 63;
        t[r][c] = hb[(size_t)(bx * 64 + r) * Fout + by * 64 + c];
    }
    __syncthreads();
    for (int i = 0; i < 16; ++i) {
        int idx = i * 256 + tid; int r = idx >> 6, c = idx & 63;
        ht[(size_t)(by * 64 + r) * N + bx * 64 + c] = t[c][r];
    }
}

// ---------------- k_attn: BM=128 rows/block, grid (M/128, NSPLIT).
// launch_bounds(512,4): VGPR cap 128, acc halved to 32 -> 2 blocks/CU so
// phase-1 (adj HBM stream) of one block overlaps phase-2 (compute) of the
// other. Phase 1: bitpack 128 x chunk adj slice into LDS (64B/thread/iter,
// coalesced, each adj elem read once device-wide). Phase 2: per 32-j step,
// stage shared 128x32 B-tile into double-buffered swizzled LDS; 8 waves
// (16 rows each) consume it; next-tile loads issued AFTER the barrier so
// the barrier's vmcnt drain doesn't expose their latency.
__global__ __launch_bounds__(512, 4)
void k_attn(const int* __restrict__ adj, const unsigned short* __restrict__ ht,
            const float* __restrict__ ssx, const float* __restrict__ sd,
            const float* __restrict__ smaxp, unsigned short* __restrict__ part,
            float* __restrict__ dpart, int N, int M, int chunk)
{
    extern __shared__ char smem[];
    unsigned* bits = (unsigned*)smem;                  // 128 * chunk/32 words
    char* btile = smem + 128 * (chunk >> 3);           // 2 x 8192 B

    const int tid = threadIdx.x;
    const int rb  = blockIdx.x * 128;
    const int j0  = blockIdx.y * chunk;
    const int wpr = chunk >> 5;                        // bitmask words per row
    const int NT  = wpr;                               // 32-j steps

    // ---- phase 1: bitpack adj[rb..rb+128)[j0..j0+chunk) into LDS
    {
        const int gpr16 = chunk >> 4;                  // 16-int groups per row
        const int gsh = 31 - __clz(gpr16);             // log2 (chunk is pow2)
        const int groups = 128 << gsh;
        unsigned short* bsh = (unsigned short*)smem;
        for (int g = tid; g < groups; g += 512) {
            const int rl = g >> gsh;
            const int jg = g & (gpr16 - 1);
            const int* ap = adj + (size_t)(rb + rl) * N + j0 + jg * 16;
            int4 v0 = *(const int4*)ap;
            int4 v1 = *(const int4*)(ap + 4);
            int4 v2 = *(const int4*)(ap + 8);
            int4 v3 = *(const int4*)(ap + 12);
            unsigned b = (unsigned)(v0.x > 0)         | ((unsigned)(v0.y > 0) << 1)
                       | ((unsigned)(v0.z > 0) << 2)  | ((unsigned)(v0.w > 0) << 3)
                       | ((unsigned)(v1.x > 0) << 4)  | ((unsigned)(v1.y > 0) << 5)
                       | ((unsigned)(v1.z > 0) << 6)  | ((unsigned)(v1.w > 0) << 7)
                       | ((unsigned)(v2.x > 0) << 8)  | ((unsigned)(v2.y > 0) << 9)
                       | ((unsigned)(v2.z > 0) << 10) | ((unsigned)(v2.w > 0) << 11)
                       | ((unsigned)(v3.x > 0) << 12) | ((unsigned)(v3.y > 0) << 13)
                       | ((unsigned)(v3.z > 0) << 14) | ((unsigned)(v3.w > 0) << 15);
            // word (jg>>1) of row rl, swizzled; ushort half = jg&1
            bsh[(rl * wpr + ((jg >> 1) ^ (rl & 7))) * 2 + (jg & 1)] = (unsigned short)b;
        }
    }

    // ---- phase 2 setup
    const int w  = tid >> 6;           // wave 0..7 -> rows [w*16, w*16+16)
    const int l  = tid & 63;
    const int am = l & 15;
    const int kg = l >> 4;
    const int ams = am & 7;

    const int rl0 = w * 16 + am;
    const int r0 = rb + rl0;
    const float s0 = sd[r0];
    const float sm = smaxp[0];
    const float vb0 = s0 + sm;
    const float m0 = fmaxf(vb0, GAT_ALPHA * vb0);
    const int bw0 = rl0 * wpr;
    const float* __restrict__ sbase = ssx + j0 + 8 * kg;

    // staging role: thread -> (f = tid>>2, jp = tid&3), 16B of ht per step
    const int fw = tid >> 2, jp = tid & 3;
    const unsigned short* __restrict__ gstage = ht + (size_t)fw * N + j0 + jp * 8;
    const int cw = fw >> 4, amw = fw & 15;
    const int wslot = (((cw & 1) << 2) | jp) ^ (amw & 7);
    const int waddr = (fw >> 5) * 2048 + amw * 128 + wslot * 16;

    // B-frag read offsets: raddr(c) = (c>>1)*2048 + (c&1 ? roffO : roffE)
    const int roffE = am * 128 + ((0 | kg) ^ ams) * 16;
    const int roffO = am * 128 + ((4 | kg) ^ ams) * 16;

    f32x4 acc[8];
    #pragma unroll
    for (int c = 0; c < 8; ++c) acc[c] = (f32x4){0.f, 0.f, 0.f, 0.f};
    float d0 = 0.f;

    __syncthreads();   // bits ready

    // prologue: REG = B-tile 0 slice; ssx step 0
    bf16x8 REG = *(const bf16x8*)gstage;
    float4 sC0 = *(const float4*)(sbase);
    float4 sC1 = *(const float4*)(sbase + 4);
    float4 sN0, sN1;

    auto PBUILD = [&](unsigned bw, const float4& u0, const float4& u1) -> bf16x8 {
        bf16x8 af;
        unsigned short* pu = (unsigned short*)&af;
        const float* f0 = (const float*)&u0;
        const float* f1 = (const float*)&u1;
        float d = 0.f;
        #pragma unroll
        for (int i = 0; i < 4; ++i) {
            float v = s0 + f0[i];
            float e = fminf(fmaxf(v, GAT_ALPHA * v) - m0, 0.f);
            float p = (bw & (1u << i)) ? __expf(e) : 0.f;
            pu[i] = f2bf(p); d += p;
        }
        #pragma unroll
        for (int i = 0; i < 4; ++i) {
            float v = s0 + f1[i];
            float e = fminf(fmaxf(v, GAT_ALPHA * v) - m0, 0.f);
            float p = (bw & (16u << i)) ? __expf(e) : 0.f;
            pu[4 + i] = f2bf(p); d += p;
        }
        d0 += d;
        return af;
    };

    auto STEP = [&](int jt, int par, float4& p0, float4& p1, float4& q0, float4& q1) {
        // stage this step's B-tile slice (REG loaded last step, vmcnt-waited here)
        *(bf16x8*)(btile + par * 8192 + waddr) = REG;
        __syncthreads();
        // B fragments first half + bitmask word
        const char* bt = btile + par * 8192;
        bf16x8 b0 = *(const bf16x8*)(bt + roffE);
        bf16x8 b1 = *(const bf16x8*)(bt + roffO);
        bf16x8 b2 = *(const bf16x8*)(bt + 2048 + roffE);
        bf16x8 b3 = *(const bf16x8*)(bt + 2048 + roffO);
        const unsigned bb = bits[bw0 + (jt ^ ams)] >> (8 * kg);
        // issue next step's global loads (consumed at next step's ds_write;
        // after the barrier so the barrier drain doesn't expose them)
        const int nj = ((jt + 1 < NT) ? jt + 1 : 0) * 32;
        REG = *(const bf16x8*)(gstage + nj);
        q0 = *(const float4*)(sbase + nj);
        q1 = *(const float4*)(sbase + nj + 4);
        // P fragment (exp chain covers LDS/L2 latency)
        bf16x8 af = PBUILD(bb, p0, p1);
        acc[0] = __builtin_amdgcn_mfma_f32_16x16x32_bf16(af, b0, acc[0], 0, 0, 0);
        acc[1] = __builtin_amdgcn_mfma_f32_16x16x32_bf16(af, b1, acc[1], 0, 0, 0);
        acc[2] = __builtin_amdgcn_mfma_f32_16x16x32_bf16(af, b2, acc[2], 0, 0, 0);
        acc[3] = __builtin_amdgcn_mfma_f32_16x16x32_bf16(af, b3, acc[3], 0, 0, 0);
        bf16x8 b4 = *(const bf16x8*)(bt + 4096 + roffE);
        bf16x8 b5 = *(const bf16x8*)(bt + 4096 + roffO);
        bf16x8 b6 = *(const bf16x8*)(bt + 6144 + roffE);
        bf16x8 b7 = *(const bf16x8*)(bt + 6144 + roffO);
        acc[4] = __builtin_amdgcn_mfma_f32_16x16x32_bf16(af, b4, acc[4], 0, 0, 0);
        acc[5] = __builtin_amdgcn_mfma_f32_16x16x32_bf16(af, b5, acc[5], 0, 0, 0);
        acc[6] = __builtin_amdgcn_mfma_f32_16x16x32_bf16(af, b6, acc[6], 0, 0, 0);
        acc[7] = __builtin_amdgcn_mfma_f32_16x16x32_bf16(af, b7, acc[7], 0, 0, 0);
    };

    for (int jt = 0; jt + 1 < NT; jt += 2) {
        STEP(jt,     0, sC0, sC1, sN0, sN1);
        STEP(jt + 1, 1, sN0, sN1, sC0, sC1);
    }
    if (NT & 1) STEP(NT - 1, 0, sC0, sC1, sN0, sN1);

    // ---- epilogue: denom partials (f32) + fragment-major numerator partials (bf16)
    d0 += __shfl_xor(d0, 16);
    d0 += __shfl_xor(d0, 32);
    if (kg == 0) dpart[(size_t)blockIdx.y * M + r0] = d0;

    unsigned short* pb = part + (size_t)blockIdx.y * M * 128
                       + ((((size_t)blockIdx.x * 8 + w) * 64 + l) * 32);
    #pragma unroll
    for (int ec = 0; ec < 4; ++ec) {
        const f32x4 x = acc[ec * 2];
        const f32x4 y = acc[ec * 2 + 1];
        bf16x8 pv;
        unsigned short* pp = (unsigned short*)&pv;
        pp[0] = f2bf(x[0]); pp[1] = f2bf(x[1]); pp[2] = f2bf(x[2]); pp[3] = f2bf(x[3]);
        pp[4] = f2bf(y[0]); pp[5] = f2bf(y[1]); pp[6] = f2bf(y[2]); pp[7] = f2bf(y[3]);
        *(bf16x8*)(pb + ec * 8) = pv;
    }
}

// ---------------- k_dsum: denom[r] = sum_s dpart[s][r]
__global__ __launch_bounds__(256)
void k_dsum(const float* __restrict__ dpart, float* __restrict__ denom, int M, int NS)
{
    const int r = blockIdx.x * 256 + threadIdx.x;
    if (r < M) {
        float d = 0.f;
        for (int s = 0; s < NS; ++s) d += dpart[(size_t)s * M + r];
        denom[r] = d;
    }
}

// ---------------- k_combine: out = elu( (sum_s part[s]) / denom[row] )
__global__ __launch_bounds__(256)
void k_combine(const unsigned short* __restrict__ part, const float* __restrict__ denom,
               float* __restrict__ out, int M, int NS)
{
    const int idx = blockIdx.x * 256 + threadIdx.x;       // unit of 8 bf16
    const int rbk = idx >> 11;                            // 2048 units per 128-row block
    const int rem = idx & 2047;
    const int w  = rem >> 8;                              // 256 units per wave
    const int l  = (rem >> 2) & 63;
    const int ec = rem & 3;
    const int am = l & 15, kg = l >> 4;

    float sums[8] = {0.f, 0.f, 0.f, 0.f, 0.f, 0.f, 0.f, 0.f};
    const unsigned short* p = part + (size_t)idx * 8;
    for (int s = 0; s < NS; ++s) {
        bf16x8 v = *(const bf16x8*)(p + (size_t)s * M * 128);
        const unsigned short* vp = (const unsigned short*)&v;
        #pragma unroll
        for (int i = 0; i < 8; ++i) sums[i] += bf2f(vp[i]);
    }
    const int rbase = rbk * 128 + w * 16 + kg * 4;
    #pragma unroll
    for (int reg = 0; reg < 4; ++reg) {
        const float dd = denom[rbase + reg];
        const float inv = (dd > 0.f) ? 1.f / dd : 0.f;
        #pragma unroll
        for (int half = 0; half < 2; ++half) {
            float x = sums[half * 4 + reg] * inv;
            x = (x > 0.f) ? x : expm1f(x);
            out[(size_t)(rbase + reg) * 128 + (ec * 2 + half) * 16 + am] = x;
        }
    }
}

extern "C" void kernel_launch(void* const* d_in, const int* in_sizes, int n_in,
                              void* d_out, int out_size, void* d_ws, size_t ws_size,
                              hipStream_t stream)
{
    const float* input = (const float*)d_in[0];
    const float* W     = (const float*)d_in[1];
    const float* c1    = (const float*)d_in[2];
    const float* c2    = (const float*)d_in[3];
    const int*   adj   = (const int*)d_in[4];

    const int Fout = in_sizes[2];          // c1: [Fout,1]
    const int Fin  = in_sizes[1] / Fout;   // W: [Fin,Fout]
    const int N    = in_sizes[0] / Fin;    // input: [N,Fin]
    const int M    = out_size / Fout;
    float* out = (float*)d_out;

    char* ws = (char*)d_ws;
    const size_t o_hb   = 0;
    const size_t o_ht   = o_hb + (size_t)N * Fout * 2;
    const size_t o_ssx  = o_ht + (size_t)N * Fout * 2;
    const size_t o_sd   = o_ssx + (size_t)N * 4;
    const size_t o_smax = o_sd + (size_t)N * 4;
    const size_t o_den  = o_smax + 64;
    const size_t o_dpart = o_den + (((size_t)M * 4 + 63) & ~63ULL);

    int NS = 16;
    size_t o_part = 0;
    while (NS >= 1) {
        size_t op = (o_dpart + (size_t)NS * M * 4 + 15) & ~15ULL;
        if (op + (size_t)NS * M * Fout * 2 <= ws_size) { o_part = op; break; }
        NS >>= 1;
    }
    const int chunk = N / NS;

    unsigned short* hb = (unsigned short*)(ws + o_hb);
    unsigned short* ht = (unsigned short*)(ws + o_ht);
    float* ssx   = (float*)(ws + o_ssx);
    float* sd    = (float*)(ws + o_sd);
    float* smax  = (float*)(ws + o_smax);
    float* denom = (float*)(ws + o_den);
    float* dpart = (float*)(ws + o_dpart);
    unsigned short* part = (unsigned short*)(ws + o_part);

    k_prep<<<N / 4, 512, 0, stream>>>(input, W, c1, c2, hb, ssx, sd, N, Fin, Fout);
    k_smax<<<1, 1024, 0, stream>>>(ssx, smax, N);
    k_transpose<<<dim3(N / 64, Fout / 64), 256, 0, stream>>>(hb, ht, N, Fout);

    const size_t smem_bytes = 128 * (size_t)(chunk >> 3) + 2 * 8192;
    k_attn<<<dim3(M / 128, NS), 512, smem_bytes, stream>>>(
        adj, ht, ssx, sd, smax, part, dpart, N, M, chunk);

    k_dsum<<<(M + 255) / 256, 256, 0, stream>>>(dpart, denom, M, NS);
    k_combine<<<M * Fout / 8 / 256, 256, 0, stream>>>(part, denom, out, M, NS);
}

// Round 9
// 149.982 us; speedup vs baseline: 5.5532x; 1.0666x over previous
//
#include <hip/hip_runtime.h>
#include <math.h>

typedef __attribute__((ext_vector_type(8))) short bf16x8;
typedef __attribute__((ext_vector_type(4))) float f32x4;

#define GAT_ALPHA 0.2f
#define NS 8

static __device__ __forceinline__ unsigned short f2bf(float x) {
    unsigned u = __float_as_uint(x);
    u += 0x7fffu + ((u >> 16) & 1u);   // RNE; inputs are finite & non-NaN
    return (unsigned short)(u >> 16);
}
static __device__ __forceinline__ float bf2f(unsigned short b) {
    return __uint_as_float(((unsigned)b) << 16);
}

// ---------------- k_prep: h = input @ W (f32), per-row {rowsum, ss=h.c2, sd=h.c1}
__global__ __launch_bounds__(512)
void k_prep(const float* __restrict__ input, const float* __restrict__ W,
            const float* __restrict__ c1, const float* __restrict__ c2,
            unsigned short* __restrict__ hb, float* __restrict__ ssx,
            float* __restrict__ sd, int N, int Fin, int Fout)
{
    __shared__ float in_lds[4][256];
    __shared__ float red[4][3];
    const int tid = threadIdx.x;
    const int r0 = blockIdx.x * 4;
    for (int idx = tid; idx < 4 * Fin; idx += 512) {
        int r = idx / Fin, c = idx - r * Fin;
        in_lds[r][c] = input[(size_t)(r0 + r) * Fin + c];
    }
    if (tid < 12) ((float*)red)[tid] = 0.f;
    __syncthreads();
    const int y = tid >> 7, f = tid & 127;
    float acc = 0.f;
    for (int k = 0; k < Fin; ++k)
        acc = fmaf(in_lds[y][k], W[(size_t)k * Fout + f], acc);
    const int row = r0 + y;
    hb[(size_t)row * Fout + f] = f2bf(acc);
    float rs = acc, sv = acc * c2[f], dv = acc * c1[f];
    for (int off = 32; off > 0; off >>= 1) {
        rs += __shfl_xor(rs, off);
        sv += __shfl_xor(sv, off);
        dv += __shfl_xor(dv, off);
    }
    if ((tid & 63) == 0) {
        atomicAdd(&red[y][0], rs);
        atomicAdd(&red[y][1], sv);
        atomicAdd(&red[y][2], dv);
    }
    __syncthreads();
    if (f == 0) {
        float rsum = red[y][0];
        ssx[row] = (rsum != 0.f) ? red[y][1] : -1e30f;  // fold j-mask into score
        sd[row]  = red[y][2];
    }
}

// ---------------- k_smax: global masked max of ssx
__global__ __launch_bounds__(1024)
void k_smax(const float* __restrict__ ssx, float* __restrict__ smax, int N)
{
    __shared__ float red[16];
    const int tid = threadIdx.x;
    float m = -3e38f;
    for (int i = tid; i < N; i += 1024) m = fmaxf(m, ssx[i]);
    for (int off = 32; off > 0; off >>= 1) m = fmaxf(m, __shfl_xor(m, off));
    if ((tid & 63) == 0) red[tid >> 6] = m;
    __syncthreads();
    if (tid == 0) {
        float mm = red[0];
        for (int i = 1; i < 16; ++i) mm = fmaxf(mm, red[i]);
        smax[0] = mm;
    }
}

// ---------------- k_transpose: hb [N][Fout] -> ht [Fout][N]
__global__ __launch_bounds__(256)
void k_transpose(const unsigned short* __restrict__ hb, unsigned short* __restrict__ ht,
                 int N, int Fout)
{
    __shared__ unsigned short t[64][65];
    const int bx = blockIdx.x;   // N/64
    const int by = blockIdx.y;   // Fout/64
    const int tid = threadIdx.x;
    for (int i = 0; i < 16; ++i) {
        int idx = i * 256 + tid; int r = idx >> 6, c = idx & 63;
        t[r][c] = hb[(size_t)(bx * 64 + r) * Fout + by * 64 + c];
    }
    __syncthreads();
    for (int i = 0; i < 16; ++i) {
        int idx = i * 256 + tid; int r = idx >> 6, c = idx & 63;
        ht[(size_t)(by * 64 + r) * N + bx * 64 + c] = t[c][r];
    }
}

// ---------------- k_attn: grid (M/128, NS=8), 512 thr. Wave w = one 16-row
// i-tile; acc (8 c-groups) persists in regs over the block's full 1024-j
// range. Per 256-j chunk: stage 128x256 B-tile (64KB, swizzled) + ssx (1KB)
// in LDS once (2 barriers/chunk, 8/block). adj read per-lane, exactly once,
// dense 64B lines, flat 2-ksub-deep pipeline across chunk boundaries. Inner
// loop: regs + LDS only. Epilogue: bf16 partials (NS=8 -> 16MB) + f32 denom.
__global__ __launch_bounds__(512, 4)
void k_attn(const int* __restrict__ adj, const unsigned short* __restrict__ ht,
            const float* __restrict__ ssx, const float* __restrict__ sd,
            const float* __restrict__ smaxp, unsigned short* __restrict__ part,
            float* __restrict__ dpart, int N, int M)
{
    __shared__ char btile[65536];           // [128 f][32 slots x16B], slot^=(f&7)
    __shared__ float sxl[256];

    const int tid = threadIdx.x;
    const int w = tid >> 6, l = tid & 63, am = l & 15, kg = l >> 4, ams = am & 7;
    const int bi = blockIdx.x, bj = blockIdx.y;
    const int jch = N / NS;                  // 1024
    const int j0 = bj * jch;
    const int row = bi * 128 + w * 16 + am;  // this lane's P-row

    const float s0 = sd[row];
    const float sm = smaxp[0];
    const float vb = s0 + sm;
    const float m0 = fmaxf(vb, GAT_ALPHA * vb);   // leakyrelu of max valid score

    const int fb  = tid >> 5;      // staging: feature sub-index 0..15
    const int pos = tid & 31;      // staging: 16B slot within 512B row
    const int rbl = am * 512;      // B-read row base (bytes)

    const int* __restrict__ aptr = adj + (size_t)row * N + j0 + kg * 8;

    f32x4 acc[8];
    #pragma unroll
    for (int c = 0; c < 8; ++c) acc[c] = (f32x4){0.f, 0.f, 0.f, 0.f};
    float d0 = 0.f;

    // flat 2-deep adj pipeline (q = ch*8 + ks in [0,32))
    int4 cA0 = *(const int4*)(aptr);
    int4 cA1 = *(const int4*)(aptr + 4);
    int4 cB0 = *(const int4*)(aptr + 32);
    int4 cB1 = *(const int4*)(aptr + 36);

    auto KS = [&](int q, int4& c0, int4& c1) {
        const int ks = q & 7;
        float4 x0 = *(const float4*)&sxl[ks * 32 + kg * 8];
        float4 x1 = *(const float4*)&sxl[ks * 32 + kg * 8 + 4];
        bf16x8 af;
        {
            unsigned short* pu = (unsigned short*)&af;
            const int* ai0 = (const int*)&c0;
            const int* ai1 = (const int*)&c1;
            const float* f0 = (const float*)&x0;
            const float* f1 = (const float*)&x1;
            float d = 0.f;
            #pragma unroll
            for (int i = 0; i < 4; ++i) {
                float v = s0 + f0[i];
                float e = fminf(fmaxf(v, GAT_ALPHA * v) - m0, 0.f);
                float p = (ai0[i] > 0) ? __expf(e) : 0.f;
                pu[i] = f2bf(p); d += p;
            }
            #pragma unroll
            for (int i = 0; i < 4; ++i) {
                float v = s0 + f1[i];
                float e = fminf(fmaxf(v, GAT_ALPHA * v) - m0, 0.f);
                float p = (ai1[i] > 0) ? __expf(e) : 0.f;
                pu[4 + i] = f2bf(p); d += p;
            }
            d0 += d;
        }
        // prefetch q+2 (flat across chunk boundary; clamp redundant at tail)
        const int qq = (q + 2 < 4 * 8) ? q + 2 : 4 * 8 - 1;
        c0 = *(const int4*)(aptr + qq * 32);
        c1 = *(const int4*)(aptr + qq * 32 + 4);
        // B fragments from LDS (2-way max conflict) + MFMA
        const int sb = rbl + (((ks * 4 + kg) ^ ams) << 4);
        #pragma unroll
        for (int c = 0; c < 8; ++c) {
            bf16x8 bf = *(const bf16x8*)(btile + sb + c * 8192);
            acc[c] = __builtin_amdgcn_mfma_f32_16x16x32_bf16(af, bf, acc[c], 0, 0, 0);
        }
    };

    for (int ch = 0; ch < 4; ++ch) {
        if (ch) __syncthreads();             // btile consumed by all waves
        // stage B-tile for this 256-j chunk (coalesced; slot XOR-swizzle)
        #pragma unroll
        for (int it = 0; it < 8; ++it) {
            const int f = it * 16 + fb;
            bf16x8 v = *(const bf16x8*)(ht + (size_t)f * N + j0 + ch * 256 + pos * 8);
            *(bf16x8*)(btile + f * 512 + ((pos ^ (f & 7)) << 4)) = v;
        }
        if (tid < 64)
            *(float4*)&sxl[tid * 4] = *(const float4*)(ssx + j0 + ch * 256 + tid * 4);
        __syncthreads();
        #pragma unroll
        for (int ks = 0; ks < 8; ks += 2) {
            KS(ch * 8 + ks,     cA0, cA1);
            KS(ch * 8 + ks + 1, cB0, cB1);
        }
    }

    // ---- epilogue: denom partial (reduce over kg) + bf16 numerator partials
    d0 += __shfl_xor(d0, 16);
    d0 += __shfl_xor(d0, 32);
    if (kg == 0) dpart[(size_t)bj * M + row] = d0;

    unsigned short* pb = part + (size_t)bj * M * 128
                       + ((((size_t)bi * 8 + w) * 64 + l) * 32);
    #pragma unroll
    for (int ec = 0; ec < 4; ++ec) {
        const f32x4 x = acc[ec * 2];
        const f32x4 y = acc[ec * 2 + 1];
        bf16x8 pv;
        unsigned short* pp = (unsigned short*)&pv;
        pp[0] = f2bf(x[0]); pp[1] = f2bf(x[1]); pp[2] = f2bf(x[2]); pp[3] = f2bf(x[3]);
        pp[4] = f2bf(y[0]); pp[5] = f2bf(y[1]); pp[6] = f2bf(y[2]); pp[7] = f2bf(y[3]);
        *(bf16x8*)(pb + ec * 8) = pv;
    }
}

// ---------------- k_dsum: denom[r] = sum_s dpart[s][r]
__global__ __launch_bounds__(256)
void k_dsum(const float* __restrict__ dpart, float* __restrict__ denom, int M, int nsp)
{
    const int r = blockIdx.x * 256 + threadIdx.x;
    if (r < M) {
        float d = 0.f;
        for (int s = 0; s < nsp; ++s) d += dpart[(size_t)s * M + r];
        denom[r] = d;
    }
}

// ---------------- k_combine: out = elu( (sum_s part[s]) / denom[row] )
__global__ __launch_bounds__(256)
void k_combine(const unsigned short* __restrict__ part, const float* __restrict__ denom,
               float* __restrict__ out, int M, int nsp)
{
    const int idx = blockIdx.x * 256 + threadIdx.x;       // unit of 8 bf16
    const int rbk = idx >> 11;                            // 2048 units per 128-row block
    const int rem = idx & 2047;
    const int w  = rem >> 8;                              // 256 units per wave
    const int l  = (rem >> 2) & 63;
    const int ec = rem & 3;
    const int am = l & 15, kg = l >> 4;

    float sums[8] = {0.f, 0.f, 0.f, 0.f, 0.f, 0.f, 0.f, 0.f};
    const unsigned short* p = part + (size_t)idx * 8;
    for (int s = 0; s < nsp; ++s) {
        bf16x8 v = *(const bf16x8*)(p + (size_t)s * M * 128);
        const unsigned short* vp = (const unsigned short*)&v;
        #pragma unroll
        for (int i = 0; i < 8; ++i) sums[i] += bf2f(vp[i]);
    }
    const int rbase = rbk * 128 + w * 16 + kg * 4;
    #pragma unroll
    for (int reg = 0; reg < 4; ++reg) {
        const float dd = denom[rbase + reg];
        const float inv = (dd > 0.f) ? 1.f / dd : 0.f;
        #pragma unroll
        for (int half = 0; half < 2; ++half) {
            float x = sums[half * 4 + reg] * inv;
            x = (x > 0.f) ? x : expm1f(x);
            out[(size_t)(rbase + reg) * 128 + (ec * 2 + half) * 16 + am] = x;
        }
    }
}

extern "C" void kernel_launch(void* const* d_in, const int* in_sizes, int n_in,
                              void* d_out, int out_size, void* d_ws, size_t ws_size,
                              hipStream_t stream)
{
    const float* input = (const float*)d_in[0];
    const float* W     = (const float*)d_in[1];
    const float* c1    = (const float*)d_in[2];
    const float* c2    = (const float*)d_in[3];
    const int*   adj   = (const int*)d_in[4];

    const int Fout = in_sizes[2];          // c1: [Fout,1]
    const int Fin  = in_sizes[1] / Fout;   // W: [Fin,Fout]
    const int N    = in_sizes[0] / Fin;    // input: [N,Fin]
    const int M    = out_size / Fout;
    float* out = (float*)d_out;

    char* ws = (char*)d_ws;
    const size_t o_hb   = 0;
    const size_t o_ht   = o_hb + (size_t)N * Fout * 2;
    const size_t o_ssx  = o_ht + (size_t)N * Fout * 2;
    const size_t o_sd   = o_ssx + (size_t)N * 4;
    const size_t o_smax = o_sd + (size_t)N * 4;
    const size_t o_den  = o_smax + 64;
    const size_t o_dpart = o_den + (((size_t)M * 4 + 63) & ~63ULL);
    const size_t o_part = (o_dpart + (size_t)NS * M * 4 + 63) & ~63ULL;

    unsigned short* hb = (unsigned short*)(ws + o_hb);
    unsigned short* ht = (unsigned short*)(ws + o_ht);
    float* ssx   = (float*)(ws + o_ssx);
    float* sd    = (float*)(ws + o_sd);
    float* smax  = (float*)(ws + o_smax);
    float* denom = (float*)(ws + o_den);
    float* dpart = (float*)(ws + o_dpart);
    unsigned short* part = (unsigned short*)(ws + o_part);

    k_prep<<<N / 4, 512, 0, stream>>>(input, W, c1, c2, hb, ssx, sd, N, Fin, Fout);
    k_smax<<<1, 1024, 0, stream>>>(ssx, smax, N);
    k_transpose<<<dim3(N / 64, Fout / 64), 256, 0, stream>>>(hb, ht, N, Fout);

    k_attn<<<dim3(M / 128, NS), 512, 0, stream>>>(
        adj, ht, ssx, sd, smax, part, dpart, N, M);

    k_dsum<<<(M + 255) / 256, 256, 0, stream>>>(dpart, denom, M, NS);
    k_combine<<<M * Fout / 8 / 256, 256, 0, stream>>>(part, denom, out, M, NS);
}